// Round 7
// baseline (6479.401 us; speedup 1.0000x reference)
//
#include <hip/hip_runtime.h>

typedef _Float16 f16x8 __attribute__((ext_vector_type(8)));
typedef _Float16 f16x2 __attribute__((ext_vector_type(2)));

union F16x8U { f16x8 v8; f16x2 v2[4]; };
union FP16U { _Float16 h; unsigned short u; };

__device__ __forceinline__ float dot2acc(f16x2 a, f16x2 b, float c) {
#if __has_builtin(__builtin_amdgcn_fdot2)
    return __builtin_amdgcn_fdot2(a, b, c, false);
#else
    return c + (float)a[0] * (float)b[0] + (float)a[1] * (float)b[1];
#endif
}

__device__ __forceinline__ float sigmoidf_(float x) {
    return __builtin_amdgcn_rcpf(1.f + __expf(-x));
}

__device__ __forceinline__ float tanhf_(float x) {
    float a = fabsf(x);
    float e = __expf(-2.f * a);
    float r = (1.f - e) * __builtin_amdgcn_rcpf(1.f + e);
    return copysignf(r, x);
}

// L1-bypassing, L2-served probe load (sc0 only; not MALL-coherent).
__device__ __forceinline__ unsigned ld_l2(const unsigned* p) {
    unsigned v;
    asm volatile("global_load_dword %0, %1, off sc0\n\ts_waitcnt vmcnt(0)"
                 : "=v"(v) : "v"(p) : "memory");
    return v;
}
// Plain dword store: write-through L1 -> lands in this XCD's L2.
__device__ __forceinline__ void st_l2(unsigned* p, unsigned v) {
    asm volatile("global_store_dword %0, %1, off" :: "v"(p), "v"(v) : "memory");
}

// ---------------------------------------------------------------------------
// ws layout (bytes) — IDENTICAL to the proven v5 footprint:
//   0         : whhp  55296 f16x8 chunks (884736 B) — per-thread reg layout
//   884736    : wih1p 3456 f16x8 chunks (55296 B)
//   940032    : wih2h 18432 fp16 (36864 B)
//   1048576   : sxp2  (64*2048*48 f32, 25.17 MB)
//   26214400  : exch  (2 buffers * 64*384 u32 tagged fp16, 196608 B)
// ---------------------------------------------------------------------------

// whhp chunk idx = ((q*8+ko)*96 + jl)*18 + g*6 + m : Whh1[g*384+q*96+jl][ko*48+m*8 ..+7]
// wih1p chunk idx = ((q*3+g)*96 + jl)*3 + m        : Wih1[g*384+q*96+jl][m*8 ..+7] (K pad 24)
__global__ void pack_weights(const float* __restrict__ Whh1,
                             const float* __restrict__ Wih1,
                             const float* __restrict__ Wih2,
                             _Float16* __restrict__ wsbase) {
    int tid = blockIdx.x * 256 + threadIdx.x;
    f16x8* whhp  = (f16x8*)wsbase;
    f16x8* wih1p = (f16x8*)(wsbase + 442368);
    _Float16* wih2h = wsbase + 470016;
    if (tid < 55296) {
        int c = tid % 18, thr = tid / 18;
        int g = c / 6, m = c % 6;
        int jl = thr % 96, ko = (thr / 96) % 8, q = thr / 768;
        int row = g * 384 + q * 96 + jl;
        int kb = ko * 48 + m * 8;
        f16x8 v;
#pragma unroll
        for (int i = 0; i < 8; ++i) v[i] = (_Float16)Whh1[row * 384 + kb + i];
        whhp[tid] = v;
    } else if (tid < 58752) {
        int t2 = tid - 55296;
        int m = t2 % 3, thr = t2 / 3;
        int jl = thr % 96, g = (thr / 96) % 3, q = thr / 288;
        int row = g * 384 + q * 96 + jl;
        f16x8 v;
#pragma unroll
        for (int i = 0; i < 8; ++i) {
            int kk = m * 8 + i;
            v[i] = (kk < 20) ? (_Float16)Wih1[row * 20 + kk] : (_Float16)0.f;
        }
        wih1p[t2] = v;
    } else if (tid < 77184) {
        int t3 = tid - 58752;
        wih2h[t3] = (_Float16)Wih2[t3];
    }
}

// ---------------------------------------------------------------------------
// gru1_scan v7: v5's proven 3-phase step; exchange transport upgraded.
// Block remap b=bid&63, q=bid>>6 -> a batch's quartet {b,b+64,b+128,b+192}
// is congruent mod 8 => same XCD under round-robin dispatch. Publisher
// writes each tagged word TWICE: plain store (own-XCD L2) + agent atomic
// (MALL). Identical bits -> benign race; any transport yields a valid word.
// Poller: 8 bounded sc0 L2 probes (fast when co-XCD), then one agent atomic
// probe (authoritative), repeat. Correct under ANY placement; fast under the
// measured one. Tags detect staleness; termination guaranteed.
// ---------------------------------------------------------------------------
__global__ __launch_bounds__(768, 3) void gru1_scan(
    const float* __restrict__ x, const float* __restrict__ h1_0,
    const float* __restrict__ bih1, const float* __restrict__ bhh1,
    const f16x8* __restrict__ whhp, const f16x8* __restrict__ wih1p,
    const _Float16* __restrict__ wih2h,
    float* __restrict__ sxp2g, unsigned* __restrict__ exch,
    float* __restrict__ h1f_o) {
    const int bid = blockIdx.x;
    const int b = bid & 63, q = bid >> 6;   // quartet co-XCD mapping
    const int tid = threadIdx.x;
    const int ko = tid / 96, jl = tid % 96;
    const int lq = ko >> 1;                 // k-quarter this thread's dots need

    __shared__ __align__(16) _Float16 h1h[384];
    __shared__ __align__(16) _Float16 hhist[4][384];
    __shared__ __align__(16) _Float16 xsh[2][24];
    __shared__ __align__(16) float4 part4[8 * 96];
    __shared__ float part2[4 * 12 * 65];

    // ---- weights into registers ----
    F16x8U W[18];
    {
        const f16x8* wp = whhp + ((size_t)((q * 8 + ko) * 96 + jl)) * 18;
#pragma unroll
        for (int c = 0; c < 18; ++c) W[c].v8 = wp[c];
    }
    F16x8U Wx[3];
    if (ko < 3) {
        const f16x8* wp = wih1p + ((size_t)((q * 3 + ko) * 96 + jl)) * 3;
#pragma unroll
        for (int c = 0; c < 3; ++c) Wx[c].v8 = wp[c];
    }

    float cbr = 0.f, cbz = 0.f, cxn = 0.f, chn = 0.f, hprev = 0.f;
    if (tid < 96) {
        int j = q * 96 + tid;
        cbr = bih1[j] + bhh1[j];
        cbz = bih1[384 + j] + bhh1[384 + j];
        cxn = bih1[768 + j];
        chn = bhh1[768 + j];
        hprev = h1_0[b * 384 + j];
    }
    if (tid < 384) h1h[tid] = (_Float16)h1_0[b * 384 + tid];
    const float* xb = x + (size_t)b * 40960;
    if (tid < 24) {
        xsh[0][tid] = (_Float16)((tid < 20) ? xb[tid] : 0.f);
        xsh[1][tid] = (_Float16)0.f;
    }
    // stager x prefetch register: holds x_{t+1} at iteration t entry
    float xreg = 0.f;
    if (tid >= 96 && tid < 116) xreg = xb[20 + (tid - 96)];

    unsigned* exb0 = exch + (size_t)b * 384;
    unsigned* exb1 = exch + 24576 + (size_t)b * 384;

    // remote-thread enumeration (valid when lq != q): rt in [0,576)
    const int rt = (tid < 192 * q) ? tid : tid - 192;
    const bool isloc = (lq == q);
    const int gslot = (!isloc && rt < 288) ? ((q * 96 + 96 + rt) % 384) : 0;

    const int o2 = tid >> 6, ks = tid & 63;
    const _Float16* w2row = wih2h + (q * 12 + o2) * 384 + ks * 6;

    // per-thread partial gate dots (k-window ko*48..+47) for step t+1;
    // xpar selects the xsh buffer holding x_{t+1}.
    auto gate_dots = [&](int xpar) {
        float ar = 0.f, az = 0.f, ahn = 0.f, axn = 0.f;
        const _Float16* hbase = h1h + ko * 48;
#pragma unroll
        for (int m = 0; m < 6; ++m) {
            F16x8U hv; hv.v8 = *(const f16x8*)(hbase + m * 8);
#pragma unroll
            for (int i = 0; i < 4; ++i) {
                ar  = dot2acc(W[m].v2[i],      hv.v2[i], ar);
                az  = dot2acc(W[6 + m].v2[i],  hv.v2[i], az);
                ahn = dot2acc(W[12 + m].v2[i], hv.v2[i], ahn);
            }
        }
        if (ko < 3) {
            float acc = 0.f;
            const _Float16* xs = xsh[xpar];
#pragma unroll
            for (int m = 0; m < 3; ++m) {
                F16x8U xv; xv.v8 = *(const f16x8*)(xs + m * 8);
#pragma unroll
                for (int i = 0; i < 4; ++i)
                    acc = dot2acc(Wx[m].v2[i], xv.v2[i], acc);
            }
            if (ko == 0) ar += acc;
            else if (ko == 1) az += acc;
            else axn += acc;
        }
        part4[ko * 96 + jl] = make_float4(ar, az, ahn, axn);
    };

    __syncthreads();
    gate_dots(0);          // dots for step 0 (h_0, x_0)
    __syncthreads();

    for (int t = 0; t < 2048; ++t) {
        const unsigned tag = (unsigned)(t + 1);
        unsigned* exw = ((t + 1) & 1) ? exb1 : exb0;

        // ---- phase A: owners finalize h_{t+1}; stagers refresh xsh ----
        if (tid < 96) {
            float sr = cbr, sz = cbz, snh = chn, snx = cxn;
#pragma unroll
            for (int k = 0; k < 8; ++k) {
                float4 p = part4[k * 96 + tid];
                sr += p.x; sz += p.y; snh += p.z; snx += p.w;
            }
            float r = sigmoidf_(sr), z = sigmoidf_(sz);
            float n = tanhf_(snx + r * snh);
            hprev = (1.f - z) * n + z * hprev;
            FP16U hu; hu.h = (_Float16)hprev;
            unsigned w = (tag << 16) | (unsigned)hu.u;
            st_l2(&exw[q * 96 + tid], w);                       // own-XCD L2
            __hip_atomic_store(&exw[q * 96 + tid], w,           // MALL
                               __ATOMIC_RELAXED, __HIP_MEMORY_SCOPE_AGENT);
            h1h[q * 96 + tid] = hu.h;
            hhist[t & 3][q * 96 + tid] = hu.h;
        } else if (tid < 116) {
            xsh[(t + 1) & 1][tid - 96] = (_Float16)xreg;     // x_{t+1}
            if (t + 2 < 2048) xreg = xb[(t + 2) * 20 + (tid - 96)];
        }
        __syncthreads();  // B1

        // ---- phase B: local-K dots overlap the remote-h round-trip ----
        if (isloc) {
            gate_dots((t + 1) & 1);
        } else if (rt < 288) {
            unsigned w;
            int spin = 0;
            for (;;) {
                w = ld_l2(&exw[gslot]);            // fast: own/shared L2
                if ((w >> 16) == tag) break;
                if (++spin >= 8) {
                    w = __hip_atomic_load(&exw[gslot], __ATOMIC_RELAXED,
                                          __HIP_MEMORY_SCOPE_AGENT);
                    if ((w >> 16) == tag) break;   // authoritative: MALL
                    spin = 0;
                }
            }
            FP16U hu; hu.u = (unsigned short)(w & 0xffffu);
            h1h[gslot] = hu.h;
            hhist[t & 3][gslot] = hu.h;
        }
        __syncthreads();  // B2: h_{t+1} complete in h1h

        // ---- phase C: remote-K dots; xp2 every 4 steps ----
        if (!isloc) gate_dots((t + 1) & 1);

        if ((t & 3) == 3) {
            f16x2 w0 = *(const f16x2*)(w2row);
            f16x2 w1 = *(const f16x2*)(w2row + 2);
            f16x2 w2 = *(const f16x2*)(w2row + 4);
#pragma unroll
            for (int tq = 0; tq < 4; ++tq) {
                const _Float16* hrow = hhist[tq] + ks * 6;
                float a = dot2acc(w0, *(const f16x2*)hrow, 0.f);
                a = dot2acc(w1, *(const f16x2*)(hrow + 2), a);
                a = dot2acc(w2, *(const f16x2*)(hrow + 4), a);
                part2[(tq * 12 + o2) * 65 + ks] = a;
            }
            __syncthreads();  // S3
            if (tid < 48) {
                int tq = tid / 12, o = tid % 12;
                const float* pr = &part2[(tq * 12 + o) * 65];
                float s0 = 0.f, s1 = 0.f, s2 = 0.f, s3 = 0.f;
#pragma unroll
                for (int i2 = 0; i2 < 16; ++i2) {
                    s0 += pr[i2 * 4];     s1 += pr[i2 * 4 + 1];
                    s2 += pr[i2 * 4 + 2]; s3 += pr[i2 * 4 + 3];
                }
                sxp2g[((size_t)b * 2048 + (t - 3 + tq)) * 48 + q * 12 + o] =
                    (s0 + s1) + (s2 + s3);
            }
        }
        __syncthreads();  // B3: part4 complete for next phase A
    }
    if (tid < 96) h1f_o[b * 384 + q * 96 + tid] = hprev;
}

// ---------------------------------------------------------------------------
// Tail: GRU2+ReLU+FC forward (from sxp2), then GRU3 reverse. One wave per
// batch; recurrent state replicated per-lane, re-broadcast via one LDS write
// + broadcast reads (3 shfl/step instead of 35-43). Proven 1.16 ms (r1).
// ---------------------------------------------------------------------------
__global__ __launch_bounds__(64) void tail_scan(
    const float* __restrict__ sxp2g, const float* __restrict__ h2_0,
    const float* __restrict__ h3_0,
    const float* __restrict__ Whh2, const float* __restrict__ bih2,
    const float* __restrict__ bhh2,
    const float* __restrict__ Wfc, const float* __restrict__ bfc,
    const float* __restrict__ Wih3, const float* __restrict__ Whh3,
    const float* __restrict__ bih3, const float* __restrict__ bhh3,
    float* __restrict__ xmid, float* __restrict__ xout,
    float* __restrict__ h2f_o, float* __restrict__ h3f_o) {
    const int b = blockIdx.x;
    const int l = threadIdx.x;

    __shared__ __align__(16) float hs[32];  // state broadcast staging

    // ================= loop 1: GRU2 + ReLU + FC + 2*tanh =================
    float w2r[16]; float bx2 = 0.f, bh2 = 0.f;
    if (l < 48) {
#pragma unroll
        for (int k = 0; k < 16; ++k) w2r[k] = Whh2[l * 16 + k];
        bx2 = bih2[l]; bh2 = bhh2[l];
    }
    float wfc[16]; float bf = 0.f;
    if (l < 20) {
#pragma unroll
        for (int k = 0; k < 16; ++k) wfc[k] = Wfc[l * 16 + k];
        bf = bfc[l];
    }
    float h2all[16];
    {
        const float4* hp = (const float4*)(h2_0 + b * 16);
#pragma unroll
        for (int c = 0; c < 4; ++c) {
            float4 v = hp[c];
            h2all[c * 4 + 0] = v.x; h2all[c * 4 + 1] = v.y;
            h2all[c * 4 + 2] = v.z; h2all[c * 4 + 3] = v.w;
        }
    }
    float hown = (l < 16) ? h2_0[b * 16 + l] : 0.f;

    float* xm = xmid + (size_t)b * 40960;
    const float* sx = sxp2g + (size_t)b * 98304;

    float pre[8];
#pragma unroll
    for (int i = 0; i < 8; ++i) pre[i] = (l < 48) ? sx[i * 48 + l] : 0.f;

    for (int tg = 0; tg < 256; ++tg) {
#pragma unroll
        for (int tq = 0; tq < 8; ++tq) {
            const int t = tg * 8 + tq;
            float ax = pre[tq] + bx2;
            if (l < 48 && t + 8 < 2048) pre[tq] = sx[(size_t)(t + 8) * 48 + l];
            float a0 = 0.f, a1 = 0.f;
#pragma unroll
            for (int k = 0; k < 8; ++k) {
                a0 = __builtin_fmaf(h2all[k], w2r[k], a0);
                a1 = __builtin_fmaf(h2all[8 + k], w2r[8 + k], a1);
            }
            float ah = bh2 + a0 + a1;
            float s_   = ax + ah;
            float zpre = __shfl(s_, (16 + l) & 63);
            float xn3  = __shfl(ax, (32 + l) & 63);
            float ghn  = __shfl(ah, (32 + l) & 63);
            float r2 = sigmoidf_(s_);
            float z2 = sigmoidf_(zpre);
            float n2 = tanhf_(xn3 + r2 * ghn);
            float h2n = (1.f - z2) * n2 + z2 * hown;
            if (l < 16) { hown = h2n; hs[l] = h2n; }
            __builtin_amdgcn_wave_barrier();
            {
                const float4* hv = (const float4*)hs;
#pragma unroll
                for (int c = 0; c < 4; ++c) {
                    float4 v = hv[c];
                    h2all[c * 4 + 0] = v.x; h2all[c * 4 + 1] = v.y;
                    h2all[c * 4 + 2] = v.z; h2all[c * 4 + 3] = v.w;
                }
            }
            float f0 = 0.f, f1 = 0.f;
#pragma unroll
            for (int k = 0; k < 8; ++k) {
                f0 = __builtin_fmaf(fmaxf(h2all[k], 0.f), wfc[k], f0);
                f1 = __builtin_fmaf(fmaxf(h2all[8 + k], 0.f), wfc[8 + k], f1);
            }
            float a = bf + f0 + f1;
            if (l < 20) xm[t * 20 + l] = 2.f * tanhf_(a);
        }
    }
    if (l < 16) h2f_o[b * 16 + l] = hown;

    // ================= loop 2: GRU3 over reversed xmid =================
    float wi3[20], wh3[20]; float bx3 = 0.f, bh3 = 0.f;
    if (l < 60) {
#pragma unroll
        for (int k = 0; k < 20; ++k) {
            wi3[k] = Wih3[l * 20 + k];
            wh3[k] = Whh3[l * 20 + k];
        }
        bx3 = bih3[l]; bh3 = bhh3[l];
    }
    float h3all[20];
    {
        const float4* hp = (const float4*)(h3_0 + b * 20);
#pragma unroll
        for (int c = 0; c < 5; ++c) {
            float4 v = hp[c];
            h3all[c * 4 + 0] = v.x; h3all[c * 4 + 1] = v.y;
            h3all[c * 4 + 2] = v.z; h3all[c * 4 + 3] = v.w;
        }
    }
    float h3own = (l < 20) ? h3_0[b * 20 + l] : 0.f;
    float* xo = xout + (size_t)b * 40960;

    float4 px[4][5];
#pragma unroll
    for (int i = 0; i < 4; ++i) {
        const float4* xr = (const float4*)(xm + (size_t)(2047 - i) * 20);
#pragma unroll
        for (int c = 0; c < 5; ++c) px[i][c] = xr[c];
    }

    for (int tg = 0; tg < 512; ++tg) {
#pragma unroll
        for (int tq = 0; tq < 4; ++tq) {
            const int t = 2047 - (tg * 4 + tq);
            float xv[20];
#pragma unroll
            for (int c = 0; c < 5; ++c) {
                float4 v = px[tq][c];
                xv[c * 4 + 0] = v.x; xv[c * 4 + 1] = v.y;
                xv[c * 4 + 2] = v.z; xv[c * 4 + 3] = v.w;
            }
            if (t - 4 >= 0) {
                const float4* xr = (const float4*)(xm + (size_t)(t - 4) * 20);
#pragma unroll
                for (int c = 0; c < 5; ++c) px[tq][c] = xr[c];
            }
            float x0 = 0.f, x1 = 0.f, g0 = 0.f, g1 = 0.f;
#pragma unroll
            for (int k = 0; k < 10; ++k) {
                x0 = __builtin_fmaf(xv[k], wi3[k], x0);
                x1 = __builtin_fmaf(xv[10 + k], wi3[10 + k], x1);
                g0 = __builtin_fmaf(h3all[k], wh3[k], g0);
                g1 = __builtin_fmaf(h3all[10 + k], wh3[10 + k], g1);
            }
            float ax = bx3 + x0 + x1;
            float ah = bh3 + g0 + g1;
            float s_   = ax + ah;
            float zpre = __shfl(s_, (20 + l) & 63);
            float xn_  = __shfl(ax, (40 + l) & 63);
            float ghn  = __shfl(ah, (40 + l) & 63);
            float r = sigmoidf_(s_);
            float z = sigmoidf_(zpre);
            float n = tanhf_(xn_ + r * ghn);
            float hn = (1.f - z) * n + z * h3own;
            if (l < 20) {
                h3own = hn;
                hs[l] = hn;
                xo[(size_t)(2047 - t) * 20 + l] = tanhf_(hn);
            }
            __builtin_amdgcn_wave_barrier();
#pragma unroll
            for (int c = 0; c < 5; ++c) {
                float4 v = ((const float4*)hs)[c];
                h3all[c * 4 + 0] = v.x; h3all[c * 4 + 1] = v.y;
                h3all[c * 4 + 2] = v.z; h3all[c * 4 + 3] = v.w;
            }
        }
    }
    if (l < 20) h3f_o[b * 20 + l] = h3own;
}

extern "C" void kernel_launch(void* const* d_in, const int* in_sizes, int n_in,
                              void* d_out, int out_size, void* d_ws, size_t ws_size,
                              hipStream_t stream) {
    const float* x    = (const float*)d_in[0];
    const float* h1   = (const float*)d_in[1];
    const float* h2   = (const float*)d_in[2];
    const float* h3   = (const float*)d_in[3];
    const float* Wih1 = (const float*)d_in[4];
    const float* Whh1 = (const float*)d_in[5];
    const float* bih1 = (const float*)d_in[6];
    const float* bhh1 = (const float*)d_in[7];
    const float* Wih2 = (const float*)d_in[8];
    const float* Whh2 = (const float*)d_in[9];
    const float* bih2 = (const float*)d_in[10];
    const float* bhh2 = (const float*)d_in[11];
    const float* Wih3 = (const float*)d_in[12];
    const float* Whh3 = (const float*)d_in[13];
    const float* bih3 = (const float*)d_in[14];
    const float* bhh3 = (const float*)d_in[15];
    const float* Wfc  = (const float*)d_in[16];
    const float* bfc  = (const float*)d_in[17];

    float* out  = (float*)d_out;
    float* xmid = out;                  // (64,2048,20)
    float* xout = out + 2621440;        // (64,2048,20)
    float* h1f  = out + 5242880;        // (64,384)
    float* h2f  = out + 5267456;        // (64,16)
    float* h3f  = out + 5268480;        // (64,20)

    char* ws = (char*)d_ws;
    _Float16* wsh  = (_Float16*)ws;
    float*    sxp2 = (float*)(ws + 1048576);
    unsigned* exch = (unsigned*)(ws + 26214400);

    hipMemsetAsync(exch, 0, 196608, stream);  // tags := 0 (never matches 1..2048)
    pack_weights<<<302, 256, 0, stream>>>(Whh1, Wih1, Wih2, wsh);
    gru1_scan<<<256, 768, 0, stream>>>(x, h1, bih1, bhh1,
                                       (const f16x8*)wsh,
                                       (const f16x8*)(wsh + 442368),
                                       wsh + 470016,
                                       sxp2, exch, h1f);
    tail_scan<<<64, 64, 0, stream>>>(sxp2, h2, h3,
                                     Whh2, bih2, bhh2, Wfc, bfc,
                                     Wih3, Whh3, bih3, bhh3,
                                     xmid, xout, h2f, h3f);
}

// Round 8
// 4988.987 us; speedup vs baseline: 1.2987x; 1.2987x over previous
//
#include <hip/hip_runtime.h>

typedef _Float16 f16x8 __attribute__((ext_vector_type(8)));
typedef _Float16 f16x2 __attribute__((ext_vector_type(2)));

union F16x8U { f16x8 v8; f16x2 v2[4]; };
union FP16U { _Float16 h; unsigned short u; };

__device__ __forceinline__ float dot2acc(f16x2 a, f16x2 b, float c) {
#if __has_builtin(__builtin_amdgcn_fdot2)
    return __builtin_amdgcn_fdot2(a, b, c, false);
#else
    return c + (float)a[0] * (float)b[0] + (float)a[1] * (float)b[1];
#endif
}

__device__ __forceinline__ float sigmoidf_(float x) {
    return __builtin_amdgcn_rcpf(1.f + __expf(-x));
}

__device__ __forceinline__ float tanhf_(float x) {
    float a = fabsf(x);
    float e = __expf(-2.f * a);
    float r = (1.f - e) * __builtin_amdgcn_rcpf(1.f + e);
    return copysignf(r, x);
}

// ---------------------------------------------------------------------------
// ws layout (bytes) — v5 footprint; prog lives in the pre-existing slack gap:
//   0         : whhp  55296 f16x8 chunks (884736 B) — per-thread reg layout
//   884736    : wih1p 3456 f16x8 chunks (55296 B)
//   940032    : wih2h 18432 fp16 (36864 B)
//   1000000   : prog  256 u32 progress words (1024 B)   [gap 976896..1048576]
//   1048576   : sxp2  (64*2048*48 f32, 25.17 MB)
//   26214400  : exch  (2 buffers * 64*384 u32 tagged fp16, 196608 B)
// ---------------------------------------------------------------------------

// whhp chunk idx = ((q*8+ko)*96 + jl)*18 + g*6 + m : Whh1[g*384+q*96+jl][ko*48+m*8 ..+7]
// wih1p chunk idx = ((q*3+g)*96 + jl)*3 + m        : Wih1[g*384+q*96+jl][m*8 ..+7] (K pad 24)
__global__ void pack_weights(const float* __restrict__ Whh1,
                             const float* __restrict__ Wih1,
                             const float* __restrict__ Wih2,
                             _Float16* __restrict__ wsbase) {
    int tid = blockIdx.x * 256 + threadIdx.x;
    f16x8* whhp  = (f16x8*)wsbase;
    f16x8* wih1p = (f16x8*)(wsbase + 442368);
    _Float16* wih2h = wsbase + 470016;
    if (tid < 55296) {
        int c = tid % 18, thr = tid / 18;
        int g = c / 6, m = c % 6;
        int jl = thr % 96, ko = (thr / 96) % 8, q = thr / 768;
        int row = g * 384 + q * 96 + jl;
        int kb = ko * 48 + m * 8;
        f16x8 v;
#pragma unroll
        for (int i = 0; i < 8; ++i) v[i] = (_Float16)Whh1[row * 384 + kb + i];
        whhp[tid] = v;
    } else if (tid < 58752) {
        int t2 = tid - 55296;
        int m = t2 % 3, thr = t2 / 3;
        int jl = thr % 96, g = (thr / 96) % 3, q = thr / 288;
        int row = g * 384 + q * 96 + jl;
        f16x8 v;
#pragma unroll
        for (int i = 0; i < 8; ++i) {
            int kk = m * 8 + i;
            v[i] = (kk < 20) ? (_Float16)Wih1[row * 20 + kk] : (_Float16)0.f;
        }
        wih1p[t2] = v;
    } else if (tid < 77184) {
        int t3 = tid - 58752;
        wih2h[t3] = (_Float16)Wih2[t3];
    }
}

// ---------------------------------------------------------------------------
// gru1_scan v8: 320 blocks.
//   bid < 256 : v5's PROVEN producer (b=bid>>2, q=bid&3, 3-phase step,
//               tagged u32 agent-atomic h-exchange) — unchanged except:
//               sxp2 stores are agent-atomic (MALL-visible mid-kernel) and
//               a per-(b,q) progress word is published after each group's
//               barrier drain (data-before-flag ordered by __syncthreads).
//   bid >= 256: one consumer block per batch runs tail loop1 (GRU2+ReLU+FC)
//               concurrently, polling prog with s_sleep backoff and reading
//               sxp2 via agent-atomic loads. Only wave 0 stays; waves 1-11
//               exit. Producers never wait on consumers -> deadlock-free.
// ---------------------------------------------------------------------------
__global__ __launch_bounds__(768, 3) void gru1_scan(
    const float* __restrict__ x, const float* __restrict__ h1_0,
    const float* __restrict__ bih1, const float* __restrict__ bhh1,
    const f16x8* __restrict__ whhp, const f16x8* __restrict__ wih1p,
    const _Float16* __restrict__ wih2h,
    float* __restrict__ sxp2g, unsigned* __restrict__ exch,
    unsigned* __restrict__ prog, float* __restrict__ h1f_o,
    const float* __restrict__ h2_0, const float* __restrict__ Whh2,
    const float* __restrict__ bih2, const float* __restrict__ bhh2,
    const float* __restrict__ Wfc, const float* __restrict__ bfc,
    float* __restrict__ xmid, float* __restrict__ h2f_o) {
    const int bid = blockIdx.x;
    const int tid = threadIdx.x;

    // ==================== consumer blocks: tail loop1 ====================
    if (bid >= 256) {
        const int cb = bid - 256;
        const int l = tid;
        if (l >= 64) return;               // waves 1..11 exit
        __shared__ __align__(16) float hs2[32];
        float w2r[16]; float bx2 = 0.f, bh2 = 0.f;
        if (l < 48) {
#pragma unroll
            for (int k = 0; k < 16; ++k) w2r[k] = Whh2[l * 16 + k];
            bx2 = bih2[l]; bh2 = bhh2[l];
        }
        float wfc[16]; float bf = 0.f;
        if (l < 20) {
#pragma unroll
            for (int k = 0; k < 16; ++k) wfc[k] = Wfc[l * 16 + k];
            bf = bfc[l];
        }
        float h2all[16];
        {
            const float4* hp4 = (const float4*)(h2_0 + cb * 16);
#pragma unroll
            for (int c = 0; c < 4; ++c) {
                float4 v = hp4[c];
                h2all[c * 4 + 0] = v.x; h2all[c * 4 + 1] = v.y;
                h2all[c * 4 + 2] = v.z; h2all[c * 4 + 3] = v.w;
            }
        }
        float hown = (l < 16) ? h2_0[cb * 16 + l] : 0.f;
        float* xm = xmid + (size_t)cb * 40960;
        const float* sx = sxp2g + (size_t)cb * 98304;
        unsigned* pw = prog + cb * 4 + ((l < 48) ? (l / 12) : 0);
        float pre[4] = {0.f, 0.f, 0.f, 0.f};
        if (l < 48) {
            while (__hip_atomic_load(pw, __ATOMIC_RELAXED,
                                     __HIP_MEMORY_SCOPE_AGENT) < 1u)
                __builtin_amdgcn_s_sleep(32);
#pragma unroll
            for (int i = 0; i < 4; ++i)
                pre[i] = __hip_atomic_load(&sx[i * 48 + l], __ATOMIC_RELAXED,
                                           __HIP_MEMORY_SCOPE_AGENT);
        }
        for (int g = 1; g <= 512; ++g) {
#pragma unroll
            for (int tq = 0; tq < 4; ++tq) {
                const int t = (g - 1) * 4 + tq;
                float ax = pre[tq] + bx2;
                float a0 = 0.f, a1 = 0.f;
#pragma unroll
                for (int k = 0; k < 8; ++k) {
                    a0 = __builtin_fmaf(h2all[k], w2r[k], a0);
                    a1 = __builtin_fmaf(h2all[8 + k], w2r[8 + k], a1);
                }
                float ah = bh2 + a0 + a1;
                float s_   = ax + ah;
                float zpre = __shfl(s_, (16 + l) & 63);
                float xn3  = __shfl(ax, (32 + l) & 63);
                float ghn  = __shfl(ah, (32 + l) & 63);
                float r2 = sigmoidf_(s_);
                float z2 = sigmoidf_(zpre);
                float n2 = tanhf_(xn3 + r2 * ghn);
                float h2n = (1.f - z2) * n2 + z2 * hown;
                if (l < 16) { hown = h2n; hs2[l] = h2n; }
                __builtin_amdgcn_wave_barrier();
                {
                    const float4* hv = (const float4*)hs2;
#pragma unroll
                    for (int c = 0; c < 4; ++c) {
                        float4 v = hv[c];
                        h2all[c * 4 + 0] = v.x; h2all[c * 4 + 1] = v.y;
                        h2all[c * 4 + 2] = v.z; h2all[c * 4 + 3] = v.w;
                    }
                }
                float f0 = 0.f, f1 = 0.f;
#pragma unroll
                for (int k = 0; k < 8; ++k) {
                    f0 = __builtin_fmaf(fmaxf(h2all[k], 0.f), wfc[k], f0);
                    f1 = __builtin_fmaf(fmaxf(h2all[8 + k], 0.f), wfc[8 + k], f1);
                }
                float a = bf + f0 + f1;
                if (l < 20) xm[t * 20 + l] = 2.f * tanhf_(a);
            }
            if (g < 512 && l < 48) {
                while (__hip_atomic_load(pw, __ATOMIC_RELAXED,
                                         __HIP_MEMORY_SCOPE_AGENT) <
                       (unsigned)(g + 1))
                    __builtin_amdgcn_s_sleep(32);
#pragma unroll
                for (int i = 0; i < 4; ++i)
                    pre[i] = __hip_atomic_load(&sx[(size_t)(g * 4 + i) * 48 + l],
                                               __ATOMIC_RELAXED,
                                               __HIP_MEMORY_SCOPE_AGENT);
            }
        }
        if (l < 16) h2f_o[cb * 16 + l] = hown;
        return;
    }

    // ==================== producer blocks: v5 verbatim ====================
    const int b = bid >> 2, q = bid & 3;
    const int ko = tid / 96, jl = tid % 96;
    const int lq = ko >> 1;                 // k-quarter this thread's dots need

    __shared__ __align__(16) _Float16 h1h[384];
    __shared__ __align__(16) _Float16 hhist[4][384];
    __shared__ __align__(16) _Float16 xsh[2][24];
    __shared__ __align__(16) float4 part4[8 * 96];
    __shared__ float part2[4 * 12 * 65];

    // ---- weights into registers ----
    F16x8U W[18];
    {
        const f16x8* wp = whhp + ((size_t)((q * 8 + ko) * 96 + jl)) * 18;
#pragma unroll
        for (int c = 0; c < 18; ++c) W[c].v8 = wp[c];
    }
    F16x8U Wx[3];
    if (ko < 3) {
        const f16x8* wp = wih1p + ((size_t)((q * 3 + ko) * 96 + jl)) * 3;
#pragma unroll
        for (int c = 0; c < 3; ++c) Wx[c].v8 = wp[c];
    }

    float cbr = 0.f, cbz = 0.f, cxn = 0.f, chn = 0.f, hprev = 0.f;
    if (tid < 96) {
        int j = q * 96 + tid;
        cbr = bih1[j] + bhh1[j];
        cbz = bih1[384 + j] + bhh1[384 + j];
        cxn = bih1[768 + j];
        chn = bhh1[768 + j];
        hprev = h1_0[b * 384 + j];
    }
    if (tid < 384) h1h[tid] = (_Float16)h1_0[b * 384 + tid];
    const float* xb = x + (size_t)b * 40960;
    if (tid < 24) {
        xsh[0][tid] = (_Float16)((tid < 20) ? xb[tid] : 0.f);
        xsh[1][tid] = (_Float16)0.f;
    }
    // stager x prefetch register: holds x_{t+1} at iteration t entry
    float xreg = 0.f;
    if (tid >= 96 && tid < 116) xreg = xb[20 + (tid - 96)];

    unsigned* exb0 = exch + (size_t)b * 384;
    unsigned* exb1 = exch + 24576 + (size_t)b * 384;

    // remote-thread enumeration (valid when lq != q): rt in [0,576)
    const int rt = (tid < 192 * q) ? tid : tid - 192;
    const bool isloc = (lq == q);
    const int gslot = (!isloc && rt < 288) ? ((q * 96 + 96 + rt) % 384) : 0;

    const int o2 = tid >> 6, ks = tid & 63;
    const _Float16* w2row = wih2h + (q * 12 + o2) * 384 + ks * 6;

    // per-thread partial gate dots (k-window ko*48..+47) for step t+1;
    // xpar selects the xsh buffer holding x_{t+1}.
    auto gate_dots = [&](int xpar) {
        float ar = 0.f, az = 0.f, ahn = 0.f, axn = 0.f;
        const _Float16* hbase = h1h + ko * 48;
#pragma unroll
        for (int m = 0; m < 6; ++m) {
            F16x8U hv; hv.v8 = *(const f16x8*)(hbase + m * 8);
#pragma unroll
            for (int i = 0; i < 4; ++i) {
                ar  = dot2acc(W[m].v2[i],      hv.v2[i], ar);
                az  = dot2acc(W[6 + m].v2[i],  hv.v2[i], az);
                ahn = dot2acc(W[12 + m].v2[i], hv.v2[i], ahn);
            }
        }
        if (ko < 3) {
            float acc = 0.f;
            const _Float16* xs = xsh[xpar];
#pragma unroll
            for (int m = 0; m < 3; ++m) {
                F16x8U xv; xv.v8 = *(const f16x8*)(xs + m * 8);
#pragma unroll
                for (int i = 0; i < 4; ++i)
                    acc = dot2acc(Wx[m].v2[i], xv.v2[i], acc);
            }
            if (ko == 0) ar += acc;
            else if (ko == 1) az += acc;
            else axn += acc;
        }
        part4[ko * 96 + jl] = make_float4(ar, az, ahn, axn);
    };

    __syncthreads();
    gate_dots(0);          // dots for step 0 (h_0, x_0)
    __syncthreads();

    for (int t = 0; t < 2048; ++t) {
        const unsigned tag = (unsigned)(t + 1);
        unsigned* exw = ((t + 1) & 1) ? exb1 : exb0;

        // publish progress for group t/4 (steps t-4..t-1): the previous
        // iteration's B3 barrier drained all sxp2 stores (vmcnt(0) before
        // s_barrier) -> data-before-flag is guaranteed.
        if ((t & 3) == 0 && t != 0 && tid == 0)
            __hip_atomic_store(&prog[(b << 2) | q], (unsigned)(t >> 2),
                               __ATOMIC_RELAXED, __HIP_MEMORY_SCOPE_AGENT);

        // ---- phase A: owners finalize h_{t+1}; stagers refresh xsh ----
        if (tid < 96) {
            float sr = cbr, sz = cbz, snh = chn, snx = cxn;
#pragma unroll
            for (int k = 0; k < 8; ++k) {
                float4 p = part4[k * 96 + tid];
                sr += p.x; sz += p.y; snh += p.z; snx += p.w;
            }
            float r = sigmoidf_(sr), z = sigmoidf_(sz);
            float n = tanhf_(snx + r * snh);
            hprev = (1.f - z) * n + z * hprev;
            FP16U hu; hu.h = (_Float16)hprev;
            __hip_atomic_store(&exw[q * 96 + tid], (tag << 16) | (unsigned)hu.u,
                               __ATOMIC_RELAXED, __HIP_MEMORY_SCOPE_AGENT);
            h1h[q * 96 + tid] = hu.h;
            hhist[t & 3][q * 96 + tid] = hu.h;
        } else if (tid < 116) {
            xsh[(t + 1) & 1][tid - 96] = (_Float16)xreg;     // x_{t+1}
            if (t + 2 < 2048) xreg = xb[(t + 2) * 20 + (tid - 96)];
        }
        __syncthreads();  // B1

        // ---- phase B: local-K dots overlap the remote-h MALL round-trip ----
        if (isloc) {
            gate_dots((t + 1) & 1);
        } else if (rt < 288) {
            unsigned w;
            do {
                w = __hip_atomic_load(&exw[gslot], __ATOMIC_RELAXED,
                                      __HIP_MEMORY_SCOPE_AGENT);
            } while ((w >> 16) != tag);
            FP16U hu; hu.u = (unsigned short)(w & 0xffffu);
            h1h[gslot] = hu.h;
            hhist[t & 3][gslot] = hu.h;
        }
        __syncthreads();  // B2: h_{t+1} complete in h1h

        // ---- phase C: remote-K dots; xp2 every 4 steps ----
        if (!isloc) gate_dots((t + 1) & 1);

        if ((t & 3) == 3) {
            f16x2 w0 = *(const f16x2*)(w2row);
            f16x2 w1 = *(const f16x2*)(w2row + 2);
            f16x2 w2 = *(const f16x2*)(w2row + 4);
#pragma unroll
            for (int tq = 0; tq < 4; ++tq) {
                const _Float16* hrow = hhist[tq] + ks * 6;
                float a = dot2acc(w0, *(const f16x2*)hrow, 0.f);
                a = dot2acc(w1, *(const f16x2*)(hrow + 2), a);
                a = dot2acc(w2, *(const f16x2*)(hrow + 4), a);
                part2[(tq * 12 + o2) * 65 + ks] = a;
            }
            __syncthreads();  // S3
            if (tid < 48) {
                int tq = tid / 12, o = tid % 12;
                const float* pr = &part2[(tq * 12 + o) * 65];
                float s0 = 0.f, s1 = 0.f, s2 = 0.f, s3 = 0.f;
#pragma unroll
                for (int i2 = 0; i2 < 16; ++i2) {
                    s0 += pr[i2 * 4];     s1 += pr[i2 * 4 + 1];
                    s2 += pr[i2 * 4 + 2]; s3 += pr[i2 * 4 + 3];
                }
                __hip_atomic_store(
                    &sxp2g[((size_t)b * 2048 + (t - 3 + tq)) * 48 + q * 12 + o],
                    (s0 + s1) + (s2 + s3), __ATOMIC_RELAXED,
                    __HIP_MEMORY_SCOPE_AGENT);
            }
        }
        __syncthreads();  // B3: part4 complete; group stores drained
    }
    if (tid == 0)
        __hip_atomic_store(&prog[(b << 2) | q], 512u,
                           __ATOMIC_RELAXED, __HIP_MEMORY_SCOPE_AGENT);
    if (tid < 96) h1f_o[b * 384 + q * 96 + tid] = hprev;
}

// ---------------------------------------------------------------------------
// Tail v8: GRU3 over reversed xmid only (loop1 moved into gru1_scan's
// consumer blocks). One wave per batch; state replicated per-lane.
// ---------------------------------------------------------------------------
__global__ __launch_bounds__(64) void tail_scan(
    const float* __restrict__ h3_0,
    const float* __restrict__ Wih3, const float* __restrict__ Whh3,
    const float* __restrict__ bih3, const float* __restrict__ bhh3,
    const float* __restrict__ xmid, float* __restrict__ xout,
    float* __restrict__ h3f_o) {
    const int b = blockIdx.x;
    const int l = threadIdx.x;

    __shared__ __align__(16) float hs[32];  // state broadcast staging

    float wi3[20], wh3[20]; float bx3 = 0.f, bh3 = 0.f;
    if (l < 60) {
#pragma unroll
        for (int k = 0; k < 20; ++k) {
            wi3[k] = Wih3[l * 20 + k];
            wh3[k] = Whh3[l * 20 + k];
        }
        bx3 = bih3[l]; bh3 = bhh3[l];
    }
    float h3all[20];
    {
        const float4* hp = (const float4*)(h3_0 + b * 20);
#pragma unroll
        for (int c = 0; c < 5; ++c) {
            float4 v = hp[c];
            h3all[c * 4 + 0] = v.x; h3all[c * 4 + 1] = v.y;
            h3all[c * 4 + 2] = v.z; h3all[c * 4 + 3] = v.w;
        }
    }
    float h3own = (l < 20) ? h3_0[b * 20 + l] : 0.f;
    const float* xm = xmid + (size_t)b * 40960;
    float* xo = xout + (size_t)b * 40960;

    float4 px[4][5];
#pragma unroll
    for (int i = 0; i < 4; ++i) {
        const float4* xr = (const float4*)(xm + (size_t)(2047 - i) * 20);
#pragma unroll
        for (int c = 0; c < 5; ++c) px[i][c] = xr[c];
    }

    for (int tg = 0; tg < 512; ++tg) {
#pragma unroll
        for (int tq = 0; tq < 4; ++tq) {
            const int t = 2047 - (tg * 4 + tq);
            float xv[20];
#pragma unroll
            for (int c = 0; c < 5; ++c) {
                float4 v = px[tq][c];
                xv[c * 4 + 0] = v.x; xv[c * 4 + 1] = v.y;
                xv[c * 4 + 2] = v.z; xv[c * 4 + 3] = v.w;
            }
            if (t - 4 >= 0) {
                const float4* xr = (const float4*)(xm + (size_t)(t - 4) * 20);
#pragma unroll
                for (int c = 0; c < 5; ++c) px[tq][c] = xr[c];
            }
            float x0 = 0.f, x1 = 0.f, g0 = 0.f, g1 = 0.f;
#pragma unroll
            for (int k = 0; k < 10; ++k) {
                x0 = __builtin_fmaf(xv[k], wi3[k], x0);
                x1 = __builtin_fmaf(xv[10 + k], wi3[10 + k], x1);
                g0 = __builtin_fmaf(h3all[k], wh3[k], g0);
                g1 = __builtin_fmaf(h3all[10 + k], wh3[10 + k], g1);
            }
            float ax = bx3 + x0 + x1;
            float ah = bh3 + g0 + g1;
            float s_   = ax + ah;
            float zpre = __shfl(s_, (20 + l) & 63);
            float xn_  = __shfl(ax, (40 + l) & 63);
            float ghn  = __shfl(ah, (40 + l) & 63);
            float r = sigmoidf_(s_);
            float z = sigmoidf_(zpre);
            float n = tanhf_(xn_ + r * ghn);
            float hn = (1.f - z) * n + z * h3own;
            if (l < 20) {
                h3own = hn;
                hs[l] = hn;
                xo[(size_t)(2047 - t) * 20 + l] = tanhf_(hn);
            }
            __builtin_amdgcn_wave_barrier();
#pragma unroll
            for (int c = 0; c < 5; ++c) {
                float4 v = ((const float4*)hs)[c];
                h3all[c * 4 + 0] = v.x; h3all[c * 4 + 1] = v.y;
                h3all[c * 4 + 2] = v.z; h3all[c * 4 + 3] = v.w;
            }
        }
    }
    if (l < 20) h3f_o[b * 20 + l] = h3own;
}

extern "C" void kernel_launch(void* const* d_in, const int* in_sizes, int n_in,
                              void* d_out, int out_size, void* d_ws, size_t ws_size,
                              hipStream_t stream) {
    const float* x    = (const float*)d_in[0];
    const float* h1   = (const float*)d_in[1];
    const float* h2   = (const float*)d_in[2];
    const float* h3   = (const float*)d_in[3];
    const float* Wih1 = (const float*)d_in[4];
    const float* Whh1 = (const float*)d_in[5];
    const float* bih1 = (const float*)d_in[6];
    const float* bhh1 = (const float*)d_in[7];
    const float* Wih2 = (const float*)d_in[8];
    const float* Whh2 = (const float*)d_in[9];
    const float* bih2 = (const float*)d_in[10];
    const float* bhh2 = (const float*)d_in[11];
    const float* Wih3 = (const float*)d_in[12];
    const float* Whh3 = (const float*)d_in[13];
    const float* bih3 = (const float*)d_in[14];
    const float* bhh3 = (const float*)d_in[15];
    const float* Wfc  = (const float*)d_in[16];
    const float* bfc  = (const float*)d_in[17];

    float* out  = (float*)d_out;
    float* xmid = out;                  // (64,2048,20)
    float* xout = out + 2621440;        // (64,2048,20)
    float* h1f  = out + 5242880;        // (64,384)
    float* h2f  = out + 5267456;        // (64,16)
    float* h3f  = out + 5268480;        // (64,20)

    char* ws = (char*)d_ws;
    _Float16* wsh  = (_Float16*)ws;
    unsigned* prog = (unsigned*)(ws + 1000000);
    float*    sxp2 = (float*)(ws + 1048576);
    unsigned* exch = (unsigned*)(ws + 26214400);

    hipMemsetAsync(exch, 0, 196608, stream);  // tags := 0 (never matches 1..2048)
    hipMemsetAsync(prog, 0, 1024, stream);    // progress := 0
    pack_weights<<<302, 256, 0, stream>>>(Whh1, Wih1, Wih2, wsh);
    gru1_scan<<<320, 768, 0, stream>>>(x, h1, bih1, bhh1,
                                       (const f16x8*)wsh,
                                       (const f16x8*)(wsh + 442368),
                                       wsh + 470016,
                                       sxp2, exch, prog, h1f,
                                       h2, Whh2, bih2, bhh2, Wfc, bfc,
                                       xmid, h2f);
    tail_scan<<<64, 64, 0, stream>>>(h3, Wih3, Whh3, bih3, bhh3,
                                     xmid, xout, h3f);
}